// Round 16
// baseline (84.131 us; speedup 1.0000x reference)
//
#include <hip/hip_runtime.h>
#include <math.h>

#define BB 8
#define SS 4096
#define DD 1024
#define HH 16

typedef __attribute__((ext_vector_type(4))) float f32x4;
typedef __fp16 fp16x2 __attribute__((ext_vector_type(2)));
typedef _Float16 half8v __attribute__((ext_vector_type(8)));

// ws layout (no aliasing):
//   plog    [BB][SS][HH] fp32 = 2 MB   @ 0      (scaled+masked logits)
//   partial [32][BB][HH][DD]  = 16 MB  @ 6 MB
//   wh16 fp16 frag stream 32 KB        @ 22 MB
//   bred    [BB][64][HH] float2 = 64 KB @ 23 MB (per-64-row-chunk softmax partials)
//   xh      [BB][SS][DD] fp16 = 64 MB  @ 24 MB (x in fp16, side-written by k_logits)

__device__ __forceinline__ void sm_merge(float& m, float& z, float om, float oz) {
  float nm = fmaxf(m, om);
  if (nm > -INFINITY)
    z = z * __expf(m - nm) + oz * __expf(om - nm);
  m = nm;
}

// K0: W fp16 frag stream (hi only; fp16-RNE W error -> logit err ~6e-5, safe).
// Element e of lane l at K-step t <-> k = t*32+(l>>4)*8+e, col h = l&15.
__global__ __launch_bounds__(256) void k_prepw(
    const float* __restrict__ W, ushort* __restrict__ wh16) {
  int i = blockIdx.x * 256 + threadIdx.x;  // 16384
  int t = i >> 9;
  int l = (i >> 3) & 63;
  int e = i & 7;
  int d = t * 32 + (l >> 4) * 8 + e;
  int h = l & 15;
  union { _Float16 f; ushort u; } cv;
  cv.f = (_Float16)W[d * HH + h];
  wh16[i] = cv.u;
}

// x staging (R10-proven): chunk = 64 floats of K, 4 rows x 256 B per XLOAD.
#define XLOAD(dst, c)                                                          \
  _Pragma("unroll") for (int k = 0; k < 4; ++k) {                              \
    int row = k * 4 + srow;                                                    \
    dst[k] = *reinterpret_cast<const float4*>(                                 \
        xw + (size_t)row * DD + (c) * 64 + sul * 4);                           \
  }
#define XSTAGE(src, c)                                                         \
  _Pragma("unroll") for (int k = 0; k < 4; ++k) {                              \
    int row = k * 4 + srow;                                                    \
    lds4[(c) & 1][wv][row][sul ^ (row & 7)] = src[k];                          \
  }
#define WLOAD(c)                                                               \
  whf[(c) & 1][0] = bhp[(2 * (c) + 0) * 64];                                   \
  whf[(c) & 1][1] = bhp[(2 * (c) + 1) * 64];

// K1 v10: R10 engine, W-hi-only (1 MFMA/t-step) + fp16 x side-write.
// grid 512 (= 8 b x 64 s-tiles of 64 rows), block 256 = 4 independent waves.
__global__ __launch_bounds__(256, 2) void k_logits(
    const float* __restrict__ x, const ushort* __restrict__ wh16,
    const int* __restrict__ mask, float* __restrict__ plog,
    float2* __restrict__ bred, ushort* __restrict__ xh) {
  __shared__ float4 lds4[2][4][16][16];  // [buf][wave][row][unit], 32 KB
  __shared__ float2 smch[4][16];

  const int tid = threadIdx.x;
  const int lane = tid & 63;
  const int wv = __builtin_amdgcn_readfirstlane(tid >> 6);
  const int b = blockIdx.x >> 6;
  const int tile = blockIdx.x & 63;
  const int s0 = tile * 64;
  const int r15 = lane & 15;      // A row within wave tile / D col (h)
  const int kg = lane >> 4;       // k-group
  const int srow = lane >> 4;     // staging sub-row
  const int sul = lane & 15;      // staging unit (16 B)

  const float* xw = x + ((size_t)b * SS + s0 + wv * 16) * DD;
  const half8v* bhp = reinterpret_cast<const half8v*>(wh16) + lane;
  // lane's fp16 x output row: same (row, k-chunk) as its A-frag
  ushort* xhw = xh + ((size_t)b * SS + s0 + wv * 16 + r15) * DD + kg * 8;

  f32x4 acch = {0.f, 0.f, 0.f, 0.f};
  float4 st[3][4];
  half8v whf[2][2];

  XLOAD(st[0], 0);
  XLOAD(st[1], 1);
  XLOAD(st[2], 2);
  XSTAGE(st[0], 0);
  WLOAD(0);
  WLOAD(1);

#pragma unroll
  for (int c = 0; c < 16; ++c) {
    if (c < 13) { XLOAD(st[(c + 3) % 3], c + 3); }

#pragma unroll
    for (int t4 = 0; t4 < 2; ++t4) {
      const int u0 = t4 * 8 + kg * 2;
      float4 va = lds4[c & 1][wv][r15][u0 ^ (r15 & 7)];
      float4 vb = lds4[c & 1][wv][r15][(u0 + 1) ^ (r15 & 7)];
      union { fp16x2 h2[4]; half8v h8; } ax;
      ax.h2[0] = __builtin_amdgcn_cvt_pkrtz(va.x, va.y);
      ax.h2[1] = __builtin_amdgcn_cvt_pkrtz(va.z, va.w);
      ax.h2[2] = __builtin_amdgcn_cvt_pkrtz(vb.x, vb.y);
      ax.h2[3] = __builtin_amdgcn_cvt_pkrtz(vb.z, vb.w);
      acch = __builtin_amdgcn_mfma_f32_16x16x32_f16(ax.h8, whf[c & 1][t4], acch, 0, 0, 0);
      // side-write the fp16 x fragment (posted store, 16 B/lane)
      *reinterpret_cast<half8v*>(xhw + (size_t)c * 64 + t4 * 32) = ax.h8;
    }

    if (c < 14) { WLOAD(c + 2); }
    if (c < 15) { XSTAGE(st[(c + 1) % 3], c + 1); }
  }

  // epilogue: masked scaled logits -> plog; chunk (m,Z) partials -> bred.
  // D layout: col = r15 (h), row = kg*4+q (m89-verified; passed R2..R15)
  float lv[4];
  float* ob = plog + ((size_t)b * SS + s0 + wv * 16) * HH;
#pragma unroll
  for (int q = 0; q < 4; ++q) {
    int srw = kg * 4 + q;
    int msk = mask[b * SS + s0 + wv * 16 + srw];
    float v = acch[q] * 0.125f;
    lv[q] = msk ? v : -INFINITY;
    ob[(size_t)srw * HH + r15] = lv[q];
  }
  float ml = fmaxf(fmaxf(lv[0], lv[1]), fmaxf(lv[2], lv[3]));
  float zl = 0.f;
  if (ml > -INFINITY) {
#pragma unroll
    for (int q = 0; q < 4; ++q) zl += __expf(lv[q] - ml);
  }
#pragma unroll
  for (int off = 16; off < 64; off <<= 1) {
    float om = __shfl_xor(ml, off, 64);
    float oz = __shfl_xor(zl, off, 64);
    sm_merge(ml, zl, om, oz);
  }
  if (kg == 0) smch[wv][r15] = make_float2(ml, zl);
  __syncthreads();
  if (tid < 16) {
    float2 p0 = smch[0][tid];
    float m = p0.x, z = p0.y;
#pragma unroll
    for (int w = 1; w < 4; ++w) {
      float2 pw = smch[w][tid];
      sm_merge(m, z, pw.x, pw.y);
    }
    bred[((size_t)b * 64 + tile) * HH + tid] = make_float2(m, z);
  }
}

// K3: pooling from fp16 xh (64 MB), inline softmax finalize.
// grid 512 (= 8b x 32sc x 2dh), block 256; thread owns 2 d.
__global__ __launch_bounds__(256) void k_pool(
    const ushort* __restrict__ xh, const float* __restrict__ plog,
    const float2* __restrict__ bred, const int* __restrict__ mask,
    float* __restrict__ partial) {
  __shared__ float wl[128][16];
  __shared__ float fm[16], fz[16];
  const int tid = threadIdx.x;
  const int dh = blockIdx.x & 1;
  const int sc = (blockIdx.x >> 1) & 31;
  const int b = blockIdx.x >> 6;
  const int s0 = sc * 128;

  if (tid < 16) {
    float m = -INFINITY, z = 0.f;
#pragma unroll 4
    for (int c = 0; c < 64; ++c) {
      float2 p = bred[((size_t)b * 64 + c) * HH + tid];
      sm_merge(m, z, p.x, p.y);
    }
    fm[tid] = m;
    fz[tid] = (z > 0.f) ? 1.0f / z : 0.f;
  }
  __syncthreads();

  const float4* p0 = reinterpret_cast<const float4*>(plog + ((size_t)b * SS + s0) * HH);
  const int* mb = mask + b * SS + s0;
#pragma unroll
  for (int k = 0; k < 2; ++k) {
    int f = k * 256 + tid;  // float4 over [128][16]
    float4 va = p0[f];
    int msk = mb[f >> 2];
    int hb = (f & 3) * 4;
    float4 w;
    w.x = msk ? __expf(va.x - fm[hb + 0]) * fz[hb + 0] : 0.f;
    w.y = msk ? __expf(va.y - fm[hb + 1]) * fz[hb + 1] : 0.f;
    w.z = msk ? __expf(va.z - fm[hb + 2]) * fz[hb + 2] : 0.f;
    w.w = msk ? __expf(va.w - fm[hb + 3]) * fz[hb + 3] : 0.f;
    *reinterpret_cast<float4*>(&wl[0][0] + f * 4) = w;
  }
  __syncthreads();

  float2 acc[HH];
#pragma unroll
  for (int h = 0; h < HH; ++h) acc[h] = make_float2(0.f, 0.f);

  const ushort* xb = xh + ((size_t)b * SS + s0) * DD + dh * 512 + tid * 2;
  for (int s = 0; s < 128; ++s) {
    fp16x2 xv2 = *reinterpret_cast<const fp16x2*>(xb + (size_t)s * DD);
    float xvx = (float)xv2.x, xvy = (float)xv2.y;
    const float4* wrow = reinterpret_cast<const float4*>(wl[s]);
    float4 wa = wrow[0], wb_ = wrow[1], wc = wrow[2], wd = wrow[3];
    float wvv[16] = {wa.x, wa.y, wa.z, wa.w, wb_.x, wb_.y, wb_.z, wb_.w,
                     wc.x, wc.y, wc.z, wc.w, wd.x, wd.y, wd.z, wd.w};
#pragma unroll
    for (int h = 0; h < HH; ++h) {
      float w = wvv[h];
      acc[h].x += w * xvx;
      acc[h].y += w * xvy;
    }
  }

  float* pb = partial + ((size_t)sc * BB + b) * (HH * DD) + dh * 512 + tid * 2;
#pragma unroll
  for (int h = 0; h < HH; ++h)
    *reinterpret_cast<float2*>(pb + (size_t)h * DD) = acc[h];
}

// K4: reduce 32 s-chunk partials. grid 512, block 256.
__global__ __launch_bounds__(256) void k_reduce(
    const float* __restrict__ partial, float* __restrict__ out) {
  const int idx = blockIdx.x * 256 + threadIdx.x;
  float s = 0.f;
#pragma unroll
  for (int c = 0; c < 32; ++c) s += partial[(size_t)c * (BB * HH * DD) + idx];
  out[idx] = s;
}

extern "C" void kernel_launch(void* const* d_in, const int* in_sizes, int n_in,
                              void* d_out, int out_size, void* d_ws, size_t ws_size,
                              hipStream_t stream) {
  const float* x = (const float*)d_in[0];     // [8][4096][1024] fp32
  const float* W = (const float*)d_in[1];     // [1024][16] fp32
  const int* mask = (const int*)d_in[2];      // [8][4096] int32
  float* out = (float*)d_out;                 // [8][16384] fp32

  char* ws = (char*)d_ws;
  float* plog    = (float*)ws;                                   // 2 MB
  float* partial = (float*)(ws + (size_t)6 * 1024 * 1024);       // 16 MB
  ushort* wh16   = (ushort*)(ws + (size_t)22 * 1024 * 1024);     // 32 KB
  float2* bred   = (float2*)(ws + (size_t)23 * 1024 * 1024);     // 64 KB
  ushort* xh     = (ushort*)(ws + (size_t)24 * 1024 * 1024);     // 64 MB

  k_prepw<<<64, 256, 0, stream>>>(W, wh16);
  k_logits<<<512, 256, 0, stream>>>(x, wh16, mask, plog, bred, xh);
  k_pool<<<512, 256, 0, stream>>>(xh, plog, bred, mask, partial);
  k_reduce<<<512, 256, 0, stream>>>(partial, out);
}